// Round 3
// baseline (947.486 us; speedup 1.0000x reference)
//
#include <hip/hip_runtime.h>
#include <math.h>

typedef __attribute__((ext_vector_type(8))) short short8;   // 8 bf16 (MFMA A/B frag)
typedef __attribute__((ext_vector_type(4))) float f32x4;    // MFMA acc frag
typedef __attribute__((ext_vector_type(2))) float f32x2;
typedef __attribute__((ext_vector_type(4))) unsigned u32x4;

#define PI_OVER_CUTOFF 0.31415926535897932f
#define SLOPE 0.015f

__device__ __forceinline__ unsigned short f2bf(float x) {
    unsigned u = __float_as_uint(x);
    return (unsigned short)((u + 0x7FFFu + ((u >> 16) & 1u)) >> 16);   // RNE
}
// packed f32x2 -> bf16x2, RNE, one instruction. D.lo = cvt(S0), D.hi = cvt(S1).
__device__ __forceinline__ unsigned cvt_pk_bf16(float lo, float hi) {
    unsigned r;
    asm("v_cvt_pk_bf16_f32 %0, %1, %2" : "=v"(r) : "v"(lo), "v"(hi));
    return r;
}
__device__ __forceinline__ short8 pack4(unsigned a, unsigned b, unsigned c, unsigned d) {
    u32x4 t = {a, b, c, d};
    return __builtin_bit_cast(short8, t);
}
// elementwise bf16 product of two bf16x8 frags, computed in f32, repacked bf16
__device__ __forceinline__ short8 mulbf8(short8 w, short8 v) {
    u32x4 uw = __builtin_bit_cast(u32x4, w);
    u32x4 uv = __builtin_bit_cast(u32x4, v);
    unsigned r0, r1, r2, r3;
#define MB(i, r)                                                         \
    {                                                                    \
        float wl = __uint_as_float(uw[i] << 16);                         \
        float wh = __uint_as_float(uw[i] & 0xFFFF0000u);                 \
        float vl = __uint_as_float(uv[i] << 16);                         \
        float vh = __uint_as_float(uv[i] & 0xFFFF0000u);                 \
        r = cvt_pk_bf16(wl * vl, wh * vh);                               \
    }
    MB(0, r0) MB(1, r1) MB(2, r2) MB(3, r3)
#undef MB
    return pack4(r0, r1, r2, r3);
}

// ---------------- kernel 0: weights -> bf16, B^T layout, pad, fold identity ---
__global__ void prep_weights(const float* __restrict__ w1, const float* __restrict__ w2,
                             const float* __restrict__ w3, const float* __restrict__ wo,
                             unsigned short* __restrict__ w1p, unsigned short* __restrict__ w2b,
                             unsigned short* __restrict__ w3b, unsigned short* __restrict__ wob) {
    int i = blockIdx.x * 256 + threadIdx.x;
    if (i < 128 * 64) {                       // w1: [128][50] -> [128][64] zero-padded
        int c = i >> 6, k = i & 63;
        w1p[i] = (k < 50) ? f2bf(w1[c * 50 + k]) : (unsigned short)0;
    }
    if (i < 128 * 128) {
        int c = i >> 7, k = i & 127;
        w2b[i] = f2bf(w2[i]);
        w3b[i] = f2bf(w3[i]);
        wob[i] = f2bf(wo[i] + ((c == k) ? 1.0f : 0.0f));  // fold "+e" residual into weight
    }
}

// ---------------- kernel 1: vp = v @ lin_w.T  -> bf16 [N][128] -----------------
__global__ __launch_bounds__(256) void vp_gemm(const float* __restrict__ v,
                                               const float* __restrict__ lin_w,
                                               unsigned short* __restrict__ vp, int nnodes) {
    const int tid = threadIdx.x;
    const int lane = tid & 63;
    const int wv = tid >> 6;          // wave 0..3 -> col strip of 32
    const int l15 = lane & 15;
    const int l4 = lane >> 4;
    const int r0 = blockIdx.x * 64;
    const int c0 = wv * 32;

    f32x4 acc[4][2] = {};
#pragma unroll
    for (int kf = 0; kf < 4; ++kf) {
        short8 a[4];
#pragma unroll
        for (int mf = 0; mf < 4; ++mf) {
            int row = r0 + mf * 16 + l15;
            f32x4 x0 = {}, x1 = {};
            if (row < nnodes) {
                const float* p = v + (size_t)row * 128 + kf * 32 + l4 * 8;
                x0 = *reinterpret_cast<const f32x4*>(p);
                x1 = *reinterpret_cast<const f32x4*>(p + 4);
            }
            a[mf] = pack4(cvt_pk_bf16(x0[0], x0[1]), cvt_pk_bf16(x0[2], x0[3]),
                          cvt_pk_bf16(x1[0], x1[1]), cvt_pk_bf16(x1[2], x1[3]));
        }
        short8 b[2];
#pragma unroll
        for (int nf = 0; nf < 2; ++nf) {
            const float* p = lin_w + (size_t)(c0 + nf * 16 + l15) * 128 + kf * 32 + l4 * 8;
            f32x4 x0 = *reinterpret_cast<const f32x4*>(p);
            f32x4 x1 = *reinterpret_cast<const f32x4*>(p + 4);
            b[nf] = pack4(cvt_pk_bf16(x0[0], x0[1]), cvt_pk_bf16(x0[2], x0[3]),
                          cvt_pk_bf16(x1[0], x1[1]), cvt_pk_bf16(x1[2], x1[3]));
        }
#pragma unroll
        for (int mf = 0; mf < 4; ++mf)
#pragma unroll
            for (int nf = 0; nf < 2; ++nf)
                acc[mf][nf] = __builtin_amdgcn_mfma_f32_16x16x32_bf16(a[mf], b[nf], acc[mf][nf], 0, 0, 0);
    }
#pragma unroll
    for (int mf = 0; mf < 4; ++mf)
#pragma unroll
        for (int nf = 0; nf < 2; ++nf)
#pragma unroll
            for (int q = 0; q < 4; ++q) {
                int row = r0 + mf * 16 + l4 * 4 + q;
                if (row < nnodes)
                    vp[(size_t)row * 128 + c0 + nf * 16 + l15] = f2bf(acc[mf][nf][q]);
            }
}

// ---------------- kernel 2: fused edge chain, wave-independent ----------------
// Each wave: 32 edges x 128 filters, private 8KB LDS slice, NO __syncthreads.
// h round-trips through LDS with (row&15)<<4 XOR swizzle (verified conflict-free).
// vp gather is COALESCED at stage-4 A-read (8 dwordx4), multiply done in regs.
__global__ __launch_bounds__(256, 4) void fused_edge(
    const float* __restrict__ dist, const float* __restrict__ dist_emb,
    const int* __restrict__ edge_index,
    const float* __restrict__ b1, const float* __restrict__ b2,
    const float* __restrict__ b3, const float* __restrict__ bo,
    const unsigned short* __restrict__ vp,
    const unsigned short* __restrict__ w1p, const unsigned short* __restrict__ w2b,
    const unsigned short* __restrict__ w3b, const unsigned short* __restrict__ wob,
    float* __restrict__ out) {
    __shared__ __align__(16) unsigned char lds_h[4][8192];  // per-wave [32 rows][256B], swizzled

    const int tid = threadIdx.x;
    const int lane = tid & 63;
    const int wv = tid >> 6;
    const int l15 = lane & 15;
    const int l4 = lane >> 4;
    const long e0 = (long)blockIdx.x * 128 + wv * 32;
    unsigned char* hb = lds_h[wv];

    // source-node byte-row offsets for this lane's two A-rows (stage-4 gather)
    const int j0 = edge_index[e0 + l15] * 128;
    const int j1 = edge_index[e0 + 16 + l15] * 128;

    f32x4 acc[2][8];

#define EPILOGUE_TO_LDS(BIASED_LEAKY)                                               \
    _Pragma("unroll")                                                               \
    for (int mf = 0; mf < 2; ++mf)                                                  \
        _Pragma("unroll")                                                           \
        for (int nf = 0; nf < 8; ++nf) {                                            \
            f32x4 vv = acc[mf][nf];                                                 \
            _Pragma("unroll")                                                       \
            for (int q = 0; q < 4; ++q) vv[q] = fmaxf(vv[q], SLOPE * vv[q]);        \
            unsigned p01 = cvt_pk_bf16(vv[0], vv[1]);                               \
            unsigned p23 = cvt_pk_bf16(vv[2], vv[3]);                               \
            int col2 = (nf * 16 + l15) * 2;                                         \
            int rb = mf * 16 + l4 * 4;                                              \
            *(unsigned short*)(hb + (rb + 0) * 256 + (col2 ^ ((l4 * 4 + 0) << 4))) = (unsigned short)p01;         \
            *(unsigned short*)(hb + (rb + 1) * 256 + (col2 ^ ((l4 * 4 + 1) << 4))) = (unsigned short)(p01 >> 16); \
            *(unsigned short*)(hb + (rb + 2) * 256 + (col2 ^ ((l4 * 4 + 2) << 4))) = (unsigned short)p23;         \
            *(unsigned short*)(hb + (rb + 3) * 256 + (col2 ^ ((l4 * 4 + 3) << 4))) = (unsigned short)(p23 >> 16); \
        }

#define HB_READ(mf, kf) \
    (*reinterpret_cast<const short8*>(hb + ((mf) * 16 + l15) * 256 + (((kf) * 64 + l4 * 16) ^ (l15 << 4))))

    // ================= stage 1: h1 = leaky(emb @ w1p.T + b1) =================
#pragma unroll
    for (int nf = 0; nf < 8; ++nf) {
        float b = b1[nf * 16 + l15];
        acc[0][nf] = (f32x4){b, b, b, b};
        acc[1][nf] = acc[0][nf];
    }
#pragma unroll
    for (int kf = 0; kf < 2; ++kf) {
        short8 a[2];
#pragma unroll
        for (int mf = 0; mf < 2; ++mf) {
            const float* src = dist_emb + (e0 + mf * 16 + l15) * 50 + kf * 32 + l4 * 8;
            unsigned pk[4];
#pragma unroll
            for (int p = 0; p < 4; ++p) {
                int k2 = kf * 32 + l4 * 8 + 2 * p;
                f32x2 x = (k2 < 50) ? *reinterpret_cast<const f32x2*>(src + 2 * p)
                                    : (f32x2){0.f, 0.f};
                pk[p] = cvt_pk_bf16(x[0], x[1]);
            }
            a[mf] = pack4(pk[0], pk[1], pk[2], pk[3]);
        }
#pragma unroll
        for (int nf = 0; nf < 8; ++nf) {
            short8 b = *reinterpret_cast<const short8*>(w1p + (nf * 16 + l15) * 64 + kf * 32 + l4 * 8);
#pragma unroll
            for (int mf = 0; mf < 2; ++mf)
                acc[mf][nf] = __builtin_amdgcn_mfma_f32_16x16x32_bf16(a[mf], b, acc[mf][nf], 0, 0, 0);
        }
    }
    EPILOGUE_TO_LDS()

    // ================= stage 2: h2 = leaky(h1 @ w2.T + b2) ====================
    {
        f32x4 acc2[2][8];
#pragma unroll
        for (int nf = 0; nf < 8; ++nf) {
            float b = b2[nf * 16 + l15];
            acc2[0][nf] = (f32x4){b, b, b, b};
            acc2[1][nf] = acc2[0][nf];
        }
#pragma unroll
        for (int kf = 0; kf < 4; ++kf) {
            short8 a0 = HB_READ(0, kf);
            short8 a1 = HB_READ(1, kf);
#pragma unroll
            for (int nf = 0; nf < 8; ++nf) {
                short8 b = *reinterpret_cast<const short8*>(w2b + (nf * 16 + l15) * 128 + kf * 32 + l4 * 8);
                acc2[0][nf] = __builtin_amdgcn_mfma_f32_16x16x32_bf16(a0, b, acc2[0][nf], 0, 0, 0);
                acc2[1][nf] = __builtin_amdgcn_mfma_f32_16x16x32_bf16(a1, b, acc2[1][nf], 0, 0, 0);
            }
        }
#pragma unroll
        for (int mf = 0; mf < 2; ++mf)
#pragma unroll
            for (int nf = 0; nf < 8; ++nf) acc[mf][nf] = acc2[mf][nf];
    }
    EPILOGUE_TO_LDS()

    // ====== stage 3: W = (h2 @ w3.T + b3) * C  -> LDS (bf16) ==================
    {
        // dist loads issued early; cos computed in epilogue
        float dd[2][4];
#pragma unroll
        for (int mf = 0; mf < 2; ++mf)
#pragma unroll
            for (int q = 0; q < 4; ++q)
                dd[mf][q] = dist[e0 + mf * 16 + l4 * 4 + q];

        f32x4 acc3[2][8];
#pragma unroll
        for (int nf = 0; nf < 8; ++nf) {
            float b = b3[nf * 16 + l15];
            acc3[0][nf] = (f32x4){b, b, b, b};
            acc3[1][nf] = acc3[0][nf];
        }
#pragma unroll
        for (int kf = 0; kf < 4; ++kf) {
            short8 a0 = HB_READ(0, kf);
            short8 a1 = HB_READ(1, kf);
#pragma unroll
            for (int nf = 0; nf < 8; ++nf) {
                short8 b = *reinterpret_cast<const short8*>(w3b + (nf * 16 + l15) * 128 + kf * 32 + l4 * 8);
                acc3[0][nf] = __builtin_amdgcn_mfma_f32_16x16x32_bf16(a0, b, acc3[0][nf], 0, 0, 0);
                acc3[1][nf] = __builtin_amdgcn_mfma_f32_16x16x32_bf16(a1, b, acc3[1][nf], 0, 0, 0);
            }
        }
        float Cw[2][4];
#pragma unroll
        for (int mf = 0; mf < 2; ++mf)
#pragma unroll
            for (int q = 0; q < 4; ++q)
                Cw[mf][q] = 0.5f * (__cosf(dd[mf][q] * PI_OVER_CUTOFF) + 1.0f);
#pragma unroll
        for (int mf = 0; mf < 2; ++mf)
#pragma unroll
            for (int nf = 0; nf < 8; ++nf) {
                f32x4 vv = acc3[mf][nf];
#pragma unroll
                for (int q = 0; q < 4; ++q) vv[q] = vv[q] * Cw[mf][q];
                unsigned p01 = cvt_pk_bf16(vv[0], vv[1]);
                unsigned p23 = cvt_pk_bf16(vv[2], vv[3]);
                int col2 = (nf * 16 + l15) * 2;
                int rb = mf * 16 + l4 * 4;
                *(unsigned short*)(hb + (rb + 0) * 256 + (col2 ^ ((l4 * 4 + 0) << 4))) = (unsigned short)p01;
                *(unsigned short*)(hb + (rb + 1) * 256 + (col2 ^ ((l4 * 4 + 1) << 4))) = (unsigned short)(p01 >> 16);
                *(unsigned short*)(hb + (rb + 2) * 256 + (col2 ^ ((l4 * 4 + 2) << 4))) = (unsigned short)p23;
                *(unsigned short*)(hb + (rb + 3) * 256 + (col2 ^ ((l4 * 4 + 3) << 4))) = (unsigned short)(p23 >> 16);
            }
    }

    // ====== stage 4: out = (vp[j] .* h) @ (wo + I).T + bo =====================
    {
        short8 vA[2][4];
        // prefetch kf=0,1 gather rows (coalesced 16B per lane, 64B per vp row)
        vA[0][0] = *reinterpret_cast<const short8*>(vp + j0 + 0 + l4 * 8);
        vA[1][0] = *reinterpret_cast<const short8*>(vp + j1 + 0 + l4 * 8);
        vA[0][1] = *reinterpret_cast<const short8*>(vp + j0 + 32 + l4 * 8);
        vA[1][1] = *reinterpret_cast<const short8*>(vp + j1 + 32 + l4 * 8);

        f32x4 acc4[2][8];
#pragma unroll
        for (int nf = 0; nf < 8; ++nf) {
            float b = bo[nf * 16 + l15];
            acc4[0][nf] = (f32x4){b, b, b, b};
            acc4[1][nf] = acc4[0][nf];
        }
#pragma unroll
        for (int kf = 0; kf < 4; ++kf) {
            if (kf < 2) {   // software-pipeline the remaining gather loads
                vA[0][kf + 2] = *reinterpret_cast<const short8*>(vp + j0 + (kf + 2) * 32 + l4 * 8);
                vA[1][kf + 2] = *reinterpret_cast<const short8*>(vp + j1 + (kf + 2) * 32 + l4 * 8);
            }
            short8 a0 = mulbf8(HB_READ(0, kf), vA[0][kf]);
            short8 a1 = mulbf8(HB_READ(1, kf), vA[1][kf]);
#pragma unroll
            for (int nf = 0; nf < 8; ++nf) {
                short8 b = *reinterpret_cast<const short8*>(wob + (nf * 16 + l15) * 128 + kf * 32 + l4 * 8);
                acc4[0][nf] = __builtin_amdgcn_mfma_f32_16x16x32_bf16(a0, b, acc4[0][nf], 0, 0, 0);
                acc4[1][nf] = __builtin_amdgcn_mfma_f32_16x16x32_bf16(a1, b, acc4[1][nf], 0, 0, 0);
            }
        }
        float* op = out + (size_t)e0 * 128;
#pragma unroll
        for (int mf = 0; mf < 2; ++mf)
#pragma unroll
            for (int nf = 0; nf < 8; ++nf)
#pragma unroll
                for (int q = 0; q < 4; ++q)
                    op[(size_t)(mf * 16 + l4 * 4 + q) * 128 + nf * 16 + l15] = acc4[mf][nf][q];
    }
#undef EPILOGUE_TO_LDS
#undef HB_READ
}

extern "C" void kernel_launch(void* const* d_in, const int* in_sizes, int n_in,
                              void* d_out, int out_size, void* d_ws, size_t ws_size,
                              hipStream_t stream) {
    const float* v        = (const float*)d_in[0];
    const float* dist     = (const float*)d_in[1];
    const float* dist_emb = (const float*)d_in[2];
    const int*   edge_idx = (const int*)d_in[3];
    const float* lin_w    = (const float*)d_in[4];
    const float* w1 = (const float*)d_in[5];
    const float* b1 = (const float*)d_in[6];
    const float* w2 = (const float*)d_in[7];
    const float* b2 = (const float*)d_in[8];
    const float* w3 = (const float*)d_in[9];
    const float* b3 = (const float*)d_in[10];
    const float* wo = (const float*)d_in[11];
    const float* bo = (const float*)d_in[12];
    float* out = (float*)d_out;

    const int nnodes = in_sizes[0] / 128;   // 50000
    const int E = in_sizes[1];              // 1600000 (multiple of 128)

    unsigned short* vp  = (unsigned short*)d_ws;            // [nnodes][128] bf16
    unsigned short* w1p = vp + (size_t)nnodes * 128;        // [128][64]
    unsigned short* w2b = w1p + 128 * 64;                   // [128][128]
    unsigned short* w3b = w2b + 128 * 128;
    unsigned short* wob = w3b + 128 * 128;

    prep_weights<<<64, 256, 0, stream>>>(w1, w2, w3, wo, w1p, w2b, w3b, wob);
    vp_gemm<<<(nnodes + 63) / 64, 256, 0, stream>>>(v, lin_w, vp, nnodes);
    fused_edge<<<E / 128, 256, 0, stream>>>(dist, dist_emb, edge_idx,
                                            b1, b2, b3, bo, vp,
                                            w1p, w2b, w3b, wob, out);
}

// Round 4
// 854.329 us; speedup vs baseline: 1.1090x; 1.1090x over previous
//
#include <hip/hip_runtime.h>
#include <math.h>

typedef __attribute__((ext_vector_type(8))) short short8;   // 8 bf16 (MFMA A/B frag)
typedef __attribute__((ext_vector_type(4))) float f32x4;    // MFMA acc frag
typedef __attribute__((ext_vector_type(2))) float f32x2;
typedef __attribute__((ext_vector_type(4))) unsigned u32x4;

#define PI_OVER_CUTOFF 0.31415926535897932f
#define SLOPE 0.015f

__device__ __forceinline__ unsigned short f2bf(float x) {
    unsigned u = __float_as_uint(x);
    return (unsigned short)((u + 0x7FFFu + ((u >> 16) & 1u)) >> 16);   // RNE
}
// packed f32x2 -> bf16x2, RNE, one instruction. D.lo = cvt(S0), D.hi = cvt(S1).
__device__ __forceinline__ unsigned cvt_pk_bf16(float lo, float hi) {
    unsigned r;
    asm("v_cvt_pk_bf16_f32 %0, %1, %2" : "=v"(r) : "v"(lo), "v"(hi));
    return r;
}
__device__ __forceinline__ short8 pack4(unsigned a, unsigned b, unsigned c, unsigned d) {
    u32x4 t = {a, b, c, d};
    return __builtin_bit_cast(short8, t);
}
// elementwise bf16 product of two bf16x8 frags, computed in f32, repacked bf16
__device__ __forceinline__ short8 mulbf8(short8 w, short8 v) {
    u32x4 uw = __builtin_bit_cast(u32x4, w);
    u32x4 uv = __builtin_bit_cast(u32x4, v);
    unsigned r0, r1, r2, r3;
#define MB(i, r)                                                         \
    {                                                                    \
        float wl = __uint_as_float(uw[i] << 16);                         \
        float wh = __uint_as_float(uw[i] & 0xFFFF0000u);                 \
        float vl = __uint_as_float(uv[i] << 16);                         \
        float vh = __uint_as_float(uv[i] & 0xFFFF0000u);                 \
        r = cvt_pk_bf16(wl * vl, wh * vh);                               \
    }
    MB(0, r0) MB(1, r1) MB(2, r2) MB(3, r3)
#undef MB
    return pack4(r0, r1, r2, r3);
}

// ---------------- kernel 0: weights -> bf16, B^T layout, pad, fold identity ---
__global__ void prep_weights(const float* __restrict__ w1, const float* __restrict__ w2,
                             const float* __restrict__ w3, const float* __restrict__ wo,
                             unsigned short* __restrict__ w1p, unsigned short* __restrict__ w2b,
                             unsigned short* __restrict__ w3b, unsigned short* __restrict__ wob) {
    int i = blockIdx.x * 256 + threadIdx.x;
    if (i < 128 * 64) {                       // w1: [128][50] -> [128][64] zero-padded
        int c = i >> 6, k = i & 63;
        w1p[i] = (k < 50) ? f2bf(w1[c * 50 + k]) : (unsigned short)0;
    }
    if (i < 128 * 128) {
        int c = i >> 7, k = i & 127;
        w2b[i] = f2bf(w2[i]);
        w3b[i] = f2bf(w3[i]);
        wob[i] = f2bf(wo[i] + ((c == k) ? 1.0f : 0.0f));  // fold "+e" residual into weight
    }
}

// ---------------- kernel 1: vp = v @ lin_w.T  -> bf16 [N][128] -----------------
__global__ __launch_bounds__(256) void vp_gemm(const float* __restrict__ v,
                                               const float* __restrict__ lin_w,
                                               unsigned short* __restrict__ vp, int nnodes) {
    const int tid = threadIdx.x;
    const int lane = tid & 63;
    const int wv = tid >> 6;          // wave 0..3 -> col strip of 32
    const int l15 = lane & 15;
    const int l4 = lane >> 4;
    const int r0 = blockIdx.x * 64;
    const int c0 = wv * 32;

    f32x4 acc[4][2] = {};
#pragma unroll
    for (int kf = 0; kf < 4; ++kf) {
        short8 a[4];
#pragma unroll
        for (int mf = 0; mf < 4; ++mf) {
            int row = r0 + mf * 16 + l15;
            f32x4 x0 = {}, x1 = {};
            if (row < nnodes) {
                const float* p = v + (size_t)row * 128 + kf * 32 + l4 * 8;
                x0 = *reinterpret_cast<const f32x4*>(p);
                x1 = *reinterpret_cast<const f32x4*>(p + 4);
            }
            a[mf] = pack4(cvt_pk_bf16(x0[0], x0[1]), cvt_pk_bf16(x0[2], x0[3]),
                          cvt_pk_bf16(x1[0], x1[1]), cvt_pk_bf16(x1[2], x1[3]));
        }
        short8 b[2];
#pragma unroll
        for (int nf = 0; nf < 2; ++nf) {
            const float* p = lin_w + (size_t)(c0 + nf * 16 + l15) * 128 + kf * 32 + l4 * 8;
            f32x4 x0 = *reinterpret_cast<const f32x4*>(p);
            f32x4 x1 = *reinterpret_cast<const f32x4*>(p + 4);
            b[nf] = pack4(cvt_pk_bf16(x0[0], x0[1]), cvt_pk_bf16(x0[2], x0[3]),
                          cvt_pk_bf16(x1[0], x1[1]), cvt_pk_bf16(x1[2], x1[3]));
        }
#pragma unroll
        for (int mf = 0; mf < 4; ++mf)
#pragma unroll
            for (int nf = 0; nf < 2; ++nf)
                acc[mf][nf] = __builtin_amdgcn_mfma_f32_16x16x32_bf16(a[mf], b[nf], acc[mf][nf], 0, 0, 0);
    }
#pragma unroll
    for (int mf = 0; mf < 4; ++mf)
#pragma unroll
        for (int nf = 0; nf < 2; ++nf)
#pragma unroll
            for (int q = 0; q < 4; ++q) {
                int row = r0 + mf * 16 + l4 * 4 + q;
                if (row < nnodes)
                    vp[(size_t)row * 128 + c0 + nf * 16 + l15] = f2bf(acc[mf][nf][q]);
            }
}

// ---------------- kernel 2: fused edge chain, wave-independent ----------------
// Each wave: 32 edges x 128 filters, private 8KB LDS slice, NO __syncthreads.
// launch_bounds(256,3): 170-reg unified budget = 64 AGPR acc + ~100 arch, NO spill.
// Stage-4 vp gather streamed per-kf (1-ahead pipeline, 16 live VGPR).
__global__ __launch_bounds__(256, 3) void fused_edge(
    const float* __restrict__ dist, const float* __restrict__ dist_emb,
    const int* __restrict__ edge_index,
    const float* __restrict__ b1, const float* __restrict__ b2,
    const float* __restrict__ b3, const float* __restrict__ bo,
    const unsigned short* __restrict__ vp,
    const unsigned short* __restrict__ w1p, const unsigned short* __restrict__ w2b,
    const unsigned short* __restrict__ w3b, const unsigned short* __restrict__ wob,
    float* __restrict__ out) {
    __shared__ __align__(16) unsigned char lds_h[4][8192];  // per-wave [32 rows][256B], swizzled

    const int tid = threadIdx.x;
    const int lane = tid & 63;
    const int wv = tid >> 6;
    const int l15 = lane & 15;
    const int l4 = lane >> 4;
    const long e0 = (long)blockIdx.x * 128 + wv * 32;
    unsigned char* hb = lds_h[wv];

    // source-node element-row offsets for this lane's two A-rows (stage-4 gather)
    const int j0 = edge_index[e0 + l15] * 128;
    const int j1 = edge_index[e0 + 16 + l15] * 128;

    f32x4 acc[2][8];

#define EPILOGUE_TO_LDS()                                                           \
    _Pragma("unroll")                                                               \
    for (int mf = 0; mf < 2; ++mf)                                                  \
        _Pragma("unroll")                                                           \
        for (int nf = 0; nf < 8; ++nf) {                                            \
            f32x4 vv = acc[mf][nf];                                                 \
            _Pragma("unroll")                                                       \
            for (int q = 0; q < 4; ++q) vv[q] = fmaxf(vv[q], SLOPE * vv[q]);        \
            unsigned p01 = cvt_pk_bf16(vv[0], vv[1]);                               \
            unsigned p23 = cvt_pk_bf16(vv[2], vv[3]);                               \
            int col2 = (nf * 16 + l15) * 2;                                         \
            int rb = mf * 16 + l4 * 4;                                              \
            *(unsigned short*)(hb + (rb + 0) * 256 + (col2 ^ ((l4 * 4 + 0) << 4))) = (unsigned short)p01;         \
            *(unsigned short*)(hb + (rb + 1) * 256 + (col2 ^ ((l4 * 4 + 1) << 4))) = (unsigned short)(p01 >> 16); \
            *(unsigned short*)(hb + (rb + 2) * 256 + (col2 ^ ((l4 * 4 + 2) << 4))) = (unsigned short)p23;         \
            *(unsigned short*)(hb + (rb + 3) * 256 + (col2 ^ ((l4 * 4 + 3) << 4))) = (unsigned short)(p23 >> 16); \
        }

#define HB_READ(mf, kf) \
    (*reinterpret_cast<const short8*>(hb + ((mf) * 16 + l15) * 256 + (((kf) * 64 + l4 * 16) ^ (l15 << 4))))

    // ================= stage 1: h1 = leaky(emb @ w1p.T + b1) =================
#pragma unroll
    for (int nf = 0; nf < 8; ++nf) {
        float b = b1[nf * 16 + l15];
        acc[0][nf] = (f32x4){b, b, b, b};
        acc[1][nf] = acc[0][nf];
    }
#pragma unroll
    for (int kf = 0; kf < 2; ++kf) {
        short8 a[2];
#pragma unroll
        for (int mf = 0; mf < 2; ++mf) {
            const float* src = dist_emb + (e0 + mf * 16 + l15) * 50 + kf * 32 + l4 * 8;
            unsigned pk[4];
#pragma unroll
            for (int p = 0; p < 4; ++p) {
                int k2 = kf * 32 + l4 * 8 + 2 * p;
                f32x2 x = (k2 < 50) ? *reinterpret_cast<const f32x2*>(src + 2 * p)
                                    : (f32x2){0.f, 0.f};
                pk[p] = cvt_pk_bf16(x[0], x[1]);
            }
            a[mf] = pack4(pk[0], pk[1], pk[2], pk[3]);
        }
#pragma unroll
        for (int nf = 0; nf < 8; ++nf) {
            short8 b = *reinterpret_cast<const short8*>(w1p + (nf * 16 + l15) * 64 + kf * 32 + l4 * 8);
#pragma unroll
            for (int mf = 0; mf < 2; ++mf)
                acc[mf][nf] = __builtin_amdgcn_mfma_f32_16x16x32_bf16(a[mf], b, acc[mf][nf], 0, 0, 0);
        }
    }
    EPILOGUE_TO_LDS()

    // ================= stage 2: h2 = leaky(h1 @ w2.T + b2) ====================
#pragma unroll
    for (int nf = 0; nf < 8; ++nf) {
        float b = b2[nf * 16 + l15];
        acc[0][nf] = (f32x4){b, b, b, b};
        acc[1][nf] = acc[0][nf];
    }
#pragma unroll
    for (int kf = 0; kf < 4; ++kf) {
        short8 a0 = HB_READ(0, kf);
        short8 a1 = HB_READ(1, kf);
#pragma unroll
        for (int nf = 0; nf < 8; ++nf) {
            short8 b = *reinterpret_cast<const short8*>(w2b + (nf * 16 + l15) * 128 + kf * 32 + l4 * 8);
            acc[0][nf] = __builtin_amdgcn_mfma_f32_16x16x32_bf16(a0, b, acc[0][nf], 0, 0, 0);
            acc[1][nf] = __builtin_amdgcn_mfma_f32_16x16x32_bf16(a1, b, acc[1][nf], 0, 0, 0);
        }
    }
    EPILOGUE_TO_LDS()

    // ====== stage 3: W = (h2 @ w3.T + b3) * C  -> LDS (bf16) ==================
    {
        // dist loads issued early; cos computed in epilogue
        float dd[2][4];
#pragma unroll
        for (int mf = 0; mf < 2; ++mf)
#pragma unroll
            for (int q = 0; q < 4; ++q)
                dd[mf][q] = dist[e0 + mf * 16 + l4 * 4 + q];

#pragma unroll
        for (int nf = 0; nf < 8; ++nf) {
            float b = b3[nf * 16 + l15];
            acc[0][nf] = (f32x4){b, b, b, b};
            acc[1][nf] = acc[0][nf];
        }
#pragma unroll
        for (int kf = 0; kf < 4; ++kf) {
            short8 a0 = HB_READ(0, kf);
            short8 a1 = HB_READ(1, kf);
#pragma unroll
            for (int nf = 0; nf < 8; ++nf) {
                short8 b = *reinterpret_cast<const short8*>(w3b + (nf * 16 + l15) * 128 + kf * 32 + l4 * 8);
                acc[0][nf] = __builtin_amdgcn_mfma_f32_16x16x32_bf16(a0, b, acc[0][nf], 0, 0, 0);
                acc[1][nf] = __builtin_amdgcn_mfma_f32_16x16x32_bf16(a1, b, acc[1][nf], 0, 0, 0);
            }
        }
        float Cw[2][4];
#pragma unroll
        for (int mf = 0; mf < 2; ++mf)
#pragma unroll
            for (int q = 0; q < 4; ++q)
                Cw[mf][q] = 0.5f * (__cosf(dd[mf][q] * PI_OVER_CUTOFF) + 1.0f);
#pragma unroll
        for (int mf = 0; mf < 2; ++mf)
#pragma unroll
            for (int nf = 0; nf < 8; ++nf) {
                f32x4 vv = acc[mf][nf];
#pragma unroll
                for (int q = 0; q < 4; ++q) vv[q] = vv[q] * Cw[mf][q];
                unsigned p01 = cvt_pk_bf16(vv[0], vv[1]);
                unsigned p23 = cvt_pk_bf16(vv[2], vv[3]);
                int col2 = (nf * 16 + l15) * 2;
                int rb = mf * 16 + l4 * 4;
                *(unsigned short*)(hb + (rb + 0) * 256 + (col2 ^ ((l4 * 4 + 0) << 4))) = (unsigned short)p01;
                *(unsigned short*)(hb + (rb + 1) * 256 + (col2 ^ ((l4 * 4 + 1) << 4))) = (unsigned short)(p01 >> 16);
                *(unsigned short*)(hb + (rb + 2) * 256 + (col2 ^ ((l4 * 4 + 2) << 4))) = (unsigned short)p23;
                *(unsigned short*)(hb + (rb + 3) * 256 + (col2 ^ ((l4 * 4 + 3) << 4))) = (unsigned short)(p23 >> 16);
            }
    }

    // ====== stage 4: out = (vp[j] .* h) @ (wo + I).T + bo =====================
    {
#pragma unroll
        for (int nf = 0; nf < 8; ++nf) {
            float b = bo[nf * 16 + l15];
            acc[0][nf] = (f32x4){b, b, b, b};
            acc[1][nf] = acc[0][nf];
        }
        // streamed vp gather: 1-ahead pipeline, only 2x2 frags live (16 VGPR)
        short8 v0 = *reinterpret_cast<const short8*>(vp + j0 + l4 * 8);
        short8 v1 = *reinterpret_cast<const short8*>(vp + j1 + l4 * 8);
#pragma unroll
        for (int kf = 0; kf < 4; ++kf) {
            short8 n0, n1;
            if (kf < 3) {
                n0 = *reinterpret_cast<const short8*>(vp + j0 + (kf + 1) * 32 + l4 * 8);
                n1 = *reinterpret_cast<const short8*>(vp + j1 + (kf + 1) * 32 + l4 * 8);
            }
            short8 a0 = mulbf8(HB_READ(0, kf), v0);
            short8 a1 = mulbf8(HB_READ(1, kf), v1);
#pragma unroll
            for (int nf = 0; nf < 8; ++nf) {
                short8 b = *reinterpret_cast<const short8*>(wob + (nf * 16 + l15) * 128 + kf * 32 + l4 * 8);
                acc[0][nf] = __builtin_amdgcn_mfma_f32_16x16x32_bf16(a0, b, acc[0][nf], 0, 0, 0);
                acc[1][nf] = __builtin_amdgcn_mfma_f32_16x16x32_bf16(a1, b, acc[1][nf], 0, 0, 0);
            }
            v0 = n0;
            v1 = n1;
        }
        float* op = out + (size_t)e0 * 128;
#pragma unroll
        for (int mf = 0; mf < 2; ++mf)
#pragma unroll
            for (int nf = 0; nf < 8; ++nf)
#pragma unroll
                for (int q = 0; q < 4; ++q)
                    op[(size_t)(mf * 16 + l4 * 4 + q) * 128 + nf * 16 + l15] = acc[mf][nf][q];
    }
#undef EPILOGUE_TO_LDS
#undef HB_READ
}

extern "C" void kernel_launch(void* const* d_in, const int* in_sizes, int n_in,
                              void* d_out, int out_size, void* d_ws, size_t ws_size,
                              hipStream_t stream) {
    const float* v        = (const float*)d_in[0];
    const float* dist     = (const float*)d_in[1];
    const float* dist_emb = (const float*)d_in[2];
    const int*   edge_idx = (const int*)d_in[3];
    const float* lin_w    = (const float*)d_in[4];
    const float* w1 = (const float*)d_in[5];
    const float* b1 = (const float*)d_in[6];
    const float* w2 = (const float*)d_in[7];
    const float* b2 = (const float*)d_in[8];
    const float* w3 = (const float*)d_in[9];
    const float* b3 = (const float*)d_in[10];
    const float* wo = (const float*)d_in[11];
    const float* bo = (const float*)d_in[12];
    float* out = (float*)d_out;

    const int nnodes = in_sizes[0] / 128;   // 50000
    const int E = in_sizes[1];              // 1600000 (multiple of 128)

    unsigned short* vp  = (unsigned short*)d_ws;            // [nnodes][128] bf16
    unsigned short* w1p = vp + (size_t)nnodes * 128;        // [128][64]
    unsigned short* w2b = w1p + 128 * 64;                   // [128][128]
    unsigned short* w3b = w2b + 128 * 128;
    unsigned short* wob = w3b + 128 * 128;

    prep_weights<<<64, 256, 0, stream>>>(w1, w2, w3, wo, w1p, w2b, w3b, wob);
    vp_gemm<<<(nnodes + 63) / 64, 256, 0, stream>>>(v, lin_w, vp, nnodes);
    fused_edge<<<E / 128, 256, 0, stream>>>(dist, dist_emb, edge_idx,
                                            b1, b2, b3, bo, vp,
                                            w1p, w2b, w3b, wob, out);
}

// Round 5
// 636.573 us; speedup vs baseline: 1.4884x; 1.3421x over previous
//
#include <hip/hip_runtime.h>
#include <math.h>

typedef __attribute__((ext_vector_type(8))) short short8;   // 8 bf16 (MFMA A/B frag)
typedef __attribute__((ext_vector_type(4))) float f32x4;    // MFMA acc frag
typedef __attribute__((ext_vector_type(2))) float f32x2;
typedef __attribute__((ext_vector_type(4))) unsigned u32x4;

#define PI_OVER_CUTOFF 0.31415926535897932f
#define SLOPE 0.015f

__device__ __forceinline__ unsigned short f2bf(float x) {
    unsigned u = __float_as_uint(x);
    return (unsigned short)((u + 0x7FFFu + ((u >> 16) & 1u)) >> 16);   // RNE
}
// packed f32x2 -> bf16x2, RNE, one instruction. D.lo = cvt(S0), D.hi = cvt(S1).
__device__ __forceinline__ unsigned cvt_pk_bf16(float lo, float hi) {
    unsigned r;
    asm("v_cvt_pk_bf16_f32 %0, %1, %2" : "=v"(r) : "v"(lo), "v"(hi));
    return r;
}
__device__ __forceinline__ short8 pack4(unsigned a, unsigned b, unsigned c, unsigned d) {
    u32x4 t = {a, b, c, d};
    return __builtin_bit_cast(short8, t);
}
// elementwise bf16 product of two bf16x8 frags, computed in f32, repacked bf16
__device__ __forceinline__ short8 mulbf8(short8 w, short8 v) {
    u32x4 uw = __builtin_bit_cast(u32x4, w);
    u32x4 uv = __builtin_bit_cast(u32x4, v);
    unsigned r0, r1, r2, r3;
#define MB(i, r)                                                         \
    {                                                                    \
        float wl = __uint_as_float(uw[i] << 16);                         \
        float wh = __uint_as_float(uw[i] & 0xFFFF0000u);                 \
        float vl = __uint_as_float(uv[i] << 16);                         \
        float vh = __uint_as_float(uv[i] & 0xFFFF0000u);                 \
        r = cvt_pk_bf16(wl * vl, wh * vh);                               \
    }
    MB(0, r0) MB(1, r1) MB(2, r2) MB(3, r3)
#undef MB
    return pack4(r0, r1, r2, r3);
}

// ---------------- kernel 0: weights -> bf16, B^T layout, pad, fold identity ---
__global__ void prep_weights(const float* __restrict__ w1, const float* __restrict__ w2,
                             const float* __restrict__ w3, const float* __restrict__ wo,
                             unsigned short* __restrict__ w1p, unsigned short* __restrict__ w2b,
                             unsigned short* __restrict__ w3b, unsigned short* __restrict__ wob) {
    int i = blockIdx.x * 256 + threadIdx.x;
    if (i < 128 * 64) {                       // w1: [128][50] -> [128][64] zero-padded
        int c = i >> 6, k = i & 63;
        w1p[i] = (k < 50) ? f2bf(w1[c * 50 + k]) : (unsigned short)0;
    }
    if (i < 128 * 128) {
        int c = i >> 7, k = i & 127;
        w2b[i] = f2bf(w2[i]);
        w3b[i] = f2bf(w3[i]);
        wob[i] = f2bf(wo[i] + ((c == k) ? 1.0f : 0.0f));  // fold "+e" residual into weight
    }
}

// ---------------- kernel 1: vp = v @ lin_w.T  -> bf16 [N][128] -----------------
__global__ __launch_bounds__(256) void vp_gemm(const float* __restrict__ v,
                                               const float* __restrict__ lin_w,
                                               unsigned short* __restrict__ vp, int nnodes) {
    const int tid = threadIdx.x;
    const int lane = tid & 63;
    const int wv = tid >> 6;          // wave 0..3 -> col strip of 32
    const int l15 = lane & 15;
    const int l4 = lane >> 4;
    const int r0 = blockIdx.x * 64;
    const int c0 = wv * 32;

    f32x4 acc[4][2] = {};
#pragma unroll
    for (int kf = 0; kf < 4; ++kf) {
        short8 a[4];
#pragma unroll
        for (int mf = 0; mf < 4; ++mf) {
            int row = r0 + mf * 16 + l15;
            f32x4 x0 = {}, x1 = {};
            if (row < nnodes) {
                const float* p = v + (size_t)row * 128 + kf * 32 + l4 * 8;
                x0 = *reinterpret_cast<const f32x4*>(p);
                x1 = *reinterpret_cast<const f32x4*>(p + 4);
            }
            a[mf] = pack4(cvt_pk_bf16(x0[0], x0[1]), cvt_pk_bf16(x0[2], x0[3]),
                          cvt_pk_bf16(x1[0], x1[1]), cvt_pk_bf16(x1[2], x1[3]));
        }
        short8 b[2];
#pragma unroll
        for (int nf = 0; nf < 2; ++nf) {
            const float* p = lin_w + (size_t)(c0 + nf * 16 + l15) * 128 + kf * 32 + l4 * 8;
            f32x4 x0 = *reinterpret_cast<const f32x4*>(p);
            f32x4 x1 = *reinterpret_cast<const f32x4*>(p + 4);
            b[nf] = pack4(cvt_pk_bf16(x0[0], x0[1]), cvt_pk_bf16(x0[2], x0[3]),
                          cvt_pk_bf16(x1[0], x1[1]), cvt_pk_bf16(x1[2], x1[3]));
        }
#pragma unroll
        for (int mf = 0; mf < 4; ++mf)
#pragma unroll
            for (int nf = 0; nf < 2; ++nf)
                acc[mf][nf] = __builtin_amdgcn_mfma_f32_16x16x32_bf16(a[mf], b[nf], acc[mf][nf], 0, 0, 0);
    }
#pragma unroll
    for (int mf = 0; mf < 4; ++mf)
#pragma unroll
        for (int nf = 0; nf < 2; ++nf)
#pragma unroll
            for (int q = 0; q < 4; ++q) {
                int row = r0 + mf * 16 + l4 * 4 + q;
                if (row < nnodes)
                    vp[(size_t)row * 128 + c0 + nf * 16 + l15] = f2bf(acc[mf][nf][q]);
            }
}

// ---------------- kernel 2: fused edge chain, wave-independent ----------------
// Each wave: 64 edges x 128 filters (M=64: weight B-loads amortized over 2x the
// edges; MFMA:B-load = 4:1). launch_bounds(256,2): 256-reg unified budget =
// 128 acc + ~110 arch -> no spill, room for loads in flight. No __syncthreads.
__global__ __launch_bounds__(256, 2) void fused_edge(
    const float* __restrict__ dist, const float* __restrict__ dist_emb,
    const int* __restrict__ edge_index,
    const float* __restrict__ b1, const float* __restrict__ b2,
    const float* __restrict__ b3, const float* __restrict__ bo,
    const unsigned short* __restrict__ vp,
    const unsigned short* __restrict__ w1p, const unsigned short* __restrict__ w2b,
    const unsigned short* __restrict__ w3b, const unsigned short* __restrict__ wob,
    float* __restrict__ out) {
    __shared__ __align__(16) unsigned char lds_h[4][16384];  // per-wave [64 rows][256B], swizzled

    const int tid = threadIdx.x;
    const int lane = tid & 63;
    const int wv = tid >> 6;
    const int l15 = lane & 15;
    const int l4 = lane >> 4;
    const long e0 = (long)blockIdx.x * 256 + wv * 64;
    unsigned char* hb = lds_h[wv];

    // source-node element-row offsets for this lane's four A-rows (stage-4 gather)
    int jm[4];
#pragma unroll
    for (int mf = 0; mf < 4; ++mf)
        jm[mf] = edge_index[e0 + mf * 16 + l15] * 128;

    f32x4 acc[4][8];

#define EPILOGUE_TO_LDS()                                                           \
    _Pragma("unroll")                                                               \
    for (int mf = 0; mf < 4; ++mf)                                                  \
        _Pragma("unroll")                                                           \
        for (int nf = 0; nf < 8; ++nf) {                                            \
            f32x4 vv = acc[mf][nf];                                                 \
            _Pragma("unroll")                                                       \
            for (int q = 0; q < 4; ++q) vv[q] = fmaxf(vv[q], SLOPE * vv[q]);        \
            unsigned p01 = cvt_pk_bf16(vv[0], vv[1]);                               \
            unsigned p23 = cvt_pk_bf16(vv[2], vv[3]);                               \
            int col2 = (nf * 16 + l15) * 2;                                         \
            int rb = mf * 16 + l4 * 4;                                              \
            *(unsigned short*)(hb + (rb + 0) * 256 + (col2 ^ ((l4 * 4 + 0) << 4))) = (unsigned short)p01;         \
            *(unsigned short*)(hb + (rb + 1) * 256 + (col2 ^ ((l4 * 4 + 1) << 4))) = (unsigned short)(p01 >> 16); \
            *(unsigned short*)(hb + (rb + 2) * 256 + (col2 ^ ((l4 * 4 + 2) << 4))) = (unsigned short)p23;         \
            *(unsigned short*)(hb + (rb + 3) * 256 + (col2 ^ ((l4 * 4 + 3) << 4))) = (unsigned short)(p23 >> 16); \
        }

#define HB_READ(mf, kf) \
    (*reinterpret_cast<const short8*>(hb + ((mf) * 16 + l15) * 256 + (((kf) * 64 + l4 * 16) ^ (l15 << 4))))

    // ================= stage 1: h1 = leaky(emb @ w1p.T + b1) =================
#pragma unroll
    for (int nf = 0; nf < 8; ++nf) {
        float b = b1[nf * 16 + l15];
#pragma unroll
        for (int mf = 0; mf < 4; ++mf) acc[mf][nf] = (f32x4){b, b, b, b};
    }
#pragma unroll
    for (int kf = 0; kf < 2; ++kf) {
        short8 a[4];
#pragma unroll
        for (int mf = 0; mf < 4; ++mf) {
            const float* src = dist_emb + (e0 + mf * 16 + l15) * 50 + kf * 32 + l4 * 8;
            unsigned pk[4];
#pragma unroll
            for (int p = 0; p < 4; ++p) {
                int k2 = kf * 32 + l4 * 8 + 2 * p;
                f32x2 x = (k2 < 50) ? *reinterpret_cast<const f32x2*>(src + 2 * p)
                                    : (f32x2){0.f, 0.f};
                pk[p] = cvt_pk_bf16(x[0], x[1]);
            }
            a[mf] = pack4(pk[0], pk[1], pk[2], pk[3]);
        }
#pragma unroll
        for (int nf = 0; nf < 8; ++nf) {
            short8 b = *reinterpret_cast<const short8*>(w1p + (nf * 16 + l15) * 64 + kf * 32 + l4 * 8);
#pragma unroll
            for (int mf = 0; mf < 4; ++mf)
                acc[mf][nf] = __builtin_amdgcn_mfma_f32_16x16x32_bf16(a[mf], b, acc[mf][nf], 0, 0, 0);
        }
    }
    EPILOGUE_TO_LDS()

    // ================= stage 2: h2 = leaky(h1 @ w2.T + b2) ====================
#pragma unroll
    for (int nf = 0; nf < 8; ++nf) {
        float b = b2[nf * 16 + l15];
#pragma unroll
        for (int mf = 0; mf < 4; ++mf) acc[mf][nf] = (f32x4){b, b, b, b};
    }
#pragma unroll
    for (int kf = 0; kf < 4; ++kf) {
        short8 a[4];
#pragma unroll
        for (int mf = 0; mf < 4; ++mf) a[mf] = HB_READ(mf, kf);
#pragma unroll
        for (int nf = 0; nf < 8; ++nf) {
            short8 b = *reinterpret_cast<const short8*>(w2b + (nf * 16 + l15) * 128 + kf * 32 + l4 * 8);
#pragma unroll
            for (int mf = 0; mf < 4; ++mf)
                acc[mf][nf] = __builtin_amdgcn_mfma_f32_16x16x32_bf16(a[mf], b, acc[mf][nf], 0, 0, 0);
        }
    }
    EPILOGUE_TO_LDS()

    // ====== stage 3: W = (h2 @ w3.T + b3) * C  -> LDS (bf16) ==================
    {
        // dist loads issued early; cos computed in epilogue
        float dd[4][4];
#pragma unroll
        for (int mf = 0; mf < 4; ++mf)
#pragma unroll
            for (int q = 0; q < 4; ++q)
                dd[mf][q] = dist[e0 + mf * 16 + l4 * 4 + q];

#pragma unroll
        for (int nf = 0; nf < 8; ++nf) {
            float b = b3[nf * 16 + l15];
#pragma unroll
            for (int mf = 0; mf < 4; ++mf) acc[mf][nf] = (f32x4){b, b, b, b};
        }
#pragma unroll
        for (int kf = 0; kf < 4; ++kf) {
            short8 a[4];
#pragma unroll
            for (int mf = 0; mf < 4; ++mf) a[mf] = HB_READ(mf, kf);
#pragma unroll
            for (int nf = 0; nf < 8; ++nf) {
                short8 b = *reinterpret_cast<const short8*>(w3b + (nf * 16 + l15) * 128 + kf * 32 + l4 * 8);
#pragma unroll
                for (int mf = 0; mf < 4; ++mf)
                    acc[mf][nf] = __builtin_amdgcn_mfma_f32_16x16x32_bf16(a[mf], b, acc[mf][nf], 0, 0, 0);
            }
        }
        float Cw[4][4];
#pragma unroll
        for (int mf = 0; mf < 4; ++mf)
#pragma unroll
            for (int q = 0; q < 4; ++q)
                Cw[mf][q] = 0.5f * (__cosf(dd[mf][q] * PI_OVER_CUTOFF) + 1.0f);
#pragma unroll
        for (int mf = 0; mf < 4; ++mf)
#pragma unroll
            for (int nf = 0; nf < 8; ++nf) {
                f32x4 vv = acc[mf][nf];
#pragma unroll
                for (int q = 0; q < 4; ++q) vv[q] = vv[q] * Cw[mf][q];
                unsigned p01 = cvt_pk_bf16(vv[0], vv[1]);
                unsigned p23 = cvt_pk_bf16(vv[2], vv[3]);
                int col2 = (nf * 16 + l15) * 2;
                int rb = mf * 16 + l4 * 4;
                *(unsigned short*)(hb + (rb + 0) * 256 + (col2 ^ ((l4 * 4 + 0) << 4))) = (unsigned short)p01;
                *(unsigned short*)(hb + (rb + 1) * 256 + (col2 ^ ((l4 * 4 + 1) << 4))) = (unsigned short)(p01 >> 16);
                *(unsigned short*)(hb + (rb + 2) * 256 + (col2 ^ ((l4 * 4 + 2) << 4))) = (unsigned short)p23;
                *(unsigned short*)(hb + (rb + 3) * 256 + (col2 ^ ((l4 * 4 + 3) << 4))) = (unsigned short)(p23 >> 16);
            }
    }

    // ====== stage 4: out = (vp[j] .* h) @ (wo + I).T + bo =====================
    {
#pragma unroll
        for (int nf = 0; nf < 8; ++nf) {
            float b = bo[nf * 16 + l15];
#pragma unroll
            for (int mf = 0; mf < 4; ++mf) acc[mf][nf] = (f32x4){b, b, b, b};
        }
        // streamed vp gather: 1-ahead pipeline (32 live VGPR)
        short8 vv[4], nn[4];
#pragma unroll
        for (int mf = 0; mf < 4; ++mf)
            vv[mf] = *reinterpret_cast<const short8*>(vp + jm[mf] + l4 * 8);
#pragma unroll
        for (int kf = 0; kf < 4; ++kf) {
            if (kf < 3) {
#pragma unroll
                for (int mf = 0; mf < 4; ++mf)
                    nn[mf] = *reinterpret_cast<const short8*>(vp + jm[mf] + (kf + 1) * 32 + l4 * 8);
            }
            short8 a[4];
#pragma unroll
            for (int mf = 0; mf < 4; ++mf) a[mf] = mulbf8(HB_READ(mf, kf), vv[mf]);
#pragma unroll
            for (int nf = 0; nf < 8; ++nf) {
                short8 b = *reinterpret_cast<const short8*>(wob + (nf * 16 + l15) * 128 + kf * 32 + l4 * 8);
#pragma unroll
                for (int mf = 0; mf < 4; ++mf)
                    acc[mf][nf] = __builtin_amdgcn_mfma_f32_16x16x32_bf16(a[mf], b, acc[mf][nf], 0, 0, 0);
            }
#pragma unroll
            for (int mf = 0; mf < 4; ++mf) vv[mf] = nn[mf];
        }
        float* op = out + (size_t)e0 * 128;
#pragma unroll
        for (int mf = 0; mf < 4; ++mf)
#pragma unroll
            for (int nf = 0; nf < 8; ++nf)
#pragma unroll
                for (int q = 0; q < 4; ++q)
                    op[(size_t)(mf * 16 + l4 * 4 + q) * 128 + nf * 16 + l15] = acc[mf][nf][q];
    }
#undef EPILOGUE_TO_LDS
#undef HB_READ
}

extern "C" void kernel_launch(void* const* d_in, const int* in_sizes, int n_in,
                              void* d_out, int out_size, void* d_ws, size_t ws_size,
                              hipStream_t stream) {
    const float* v        = (const float*)d_in[0];
    const float* dist     = (const float*)d_in[1];
    const float* dist_emb = (const float*)d_in[2];
    const int*   edge_idx = (const int*)d_in[3];
    const float* lin_w    = (const float*)d_in[4];
    const float* w1 = (const float*)d_in[5];
    const float* b1 = (const float*)d_in[6];
    const float* w2 = (const float*)d_in[7];
    const float* b2 = (const float*)d_in[8];
    const float* w3 = (const float*)d_in[9];
    const float* b3 = (const float*)d_in[10];
    const float* wo = (const float*)d_in[11];
    const float* bo = (const float*)d_in[12];
    float* out = (float*)d_out;

    const int nnodes = in_sizes[0] / 128;   // 50000
    const int E = in_sizes[1];              // 1600000 (multiple of 256)

    unsigned short* vp  = (unsigned short*)d_ws;            // [nnodes][128] bf16
    unsigned short* w1p = vp + (size_t)nnodes * 128;        // [128][64]
    unsigned short* w2b = w1p + 128 * 64;                   // [128][128]
    unsigned short* w3b = w2b + 128 * 128;
    unsigned short* wob = w3b + 128 * 128;

    prep_weights<<<64, 256, 0, stream>>>(w1, w2, w3, wo, w1p, w2b, w3b, wob);
    vp_gemm<<<(nnodes + 63) / 64, 256, 0, stream>>>(v, lin_w, vp, nnodes);
    fused_edge<<<E / 256, 256, 0, stream>>>(dist, dist_emb, edge_idx,
                                            b1, b2, b3, bo, vp,
                                            w1p, w2b, w3b, wob, out);
}

// Round 6
// 526.939 us; speedup vs baseline: 1.7981x; 1.2081x over previous
//
#include <hip/hip_runtime.h>
#include <math.h>

typedef __attribute__((ext_vector_type(8))) short short8;   // 8 bf16 (MFMA A/B frag)
typedef __attribute__((ext_vector_type(4))) float f32x4;    // MFMA acc frag
typedef __attribute__((ext_vector_type(2))) float f32x2;
typedef __attribute__((ext_vector_type(4))) unsigned u32x4;

#define PI_OVER_CUTOFF 0.31415926535897932f
#define SLOPE 0.015f

__device__ __forceinline__ unsigned short f2bf(float x) {
    unsigned u = __float_as_uint(x);
    return (unsigned short)((u + 0x7FFFu + ((u >> 16) & 1u)) >> 16);   // RNE
}
// packed f32x2 -> bf16x2, RNE, one instruction. D.lo = cvt(S0), D.hi = cvt(S1).
__device__ __forceinline__ unsigned cvt_pk_bf16(float lo, float hi) {
    unsigned r;
    asm("v_cvt_pk_bf16_f32 %0, %1, %2" : "=v"(r) : "v"(lo), "v"(hi));
    return r;
}
__device__ __forceinline__ short8 pack4(unsigned a, unsigned b, unsigned c, unsigned d) {
    u32x4 t = {a, b, c, d};
    return __builtin_bit_cast(short8, t);
}
// elementwise bf16 product of two bf16x8 frags, computed in f32, repacked bf16
__device__ __forceinline__ short8 mulbf8(short8 w, short8 v) {
    u32x4 uw = __builtin_bit_cast(u32x4, w);
    u32x4 uv = __builtin_bit_cast(u32x4, v);
    unsigned r0, r1, r2, r3;
#define MB(i, r)                                                         \
    {                                                                    \
        float wl = __uint_as_float(uw[i] << 16);                         \
        float wh = __uint_as_float(uw[i] & 0xFFFF0000u);                 \
        float vl = __uint_as_float(uv[i] << 16);                         \
        float vh = __uint_as_float(uv[i] & 0xFFFF0000u);                 \
        r = cvt_pk_bf16(wl * vl, wh * vh);                               \
    }
    MB(0, r0) MB(1, r1) MB(2, r2) MB(3, r3)
#undef MB
    return pack4(r0, r1, r2, r3);
}

// async global(per-lane) -> LDS(wave-uniform base, lane*16B) 16-byte copy
#define GLOAD_LDS16(g, l)                                                                      \
    __builtin_amdgcn_global_load_lds((const __attribute__((address_space(1))) unsigned*)(g),   \
                                     (__attribute__((address_space(3))) unsigned*)(l), 16, 0, 0)

// ---- kernel 0: weights -> bf16, B^T layout, PRE-SWIZZLED for LDS staging -----
// element (row c, col k) stored at u16 index c*128 + (k ^ ((c&15)<<3)).
// linear global_load_lds then yields the same swizzled layout in LDS; the
// ds_read applies the identical XOR -> conflict-free (verified family, R5=0).
__global__ void prep_weights(const float* __restrict__ w1, const float* __restrict__ w2,
                             const float* __restrict__ w3, const float* __restrict__ wo,
                             unsigned short* __restrict__ w1s, unsigned short* __restrict__ w2s,
                             unsigned short* __restrict__ w3s, unsigned short* __restrict__ wos) {
    int i = blockIdx.x * 256 + threadIdx.x;
    if (i < 128 * 128) {
        int c = i >> 7, k = i & 127;
        int d = c * 128 + (k ^ ((c & 15) << 3));
        w1s[d] = (k < 50) ? f2bf(w1[c * 50 + k]) : (unsigned short)0;  // pad K 50->128
        w2s[d] = f2bf(w2[i]);
        w3s[d] = f2bf(w3[i]);
        wos[d] = f2bf(wo[i] + ((c == k) ? 1.0f : 0.0f));  // fold "+e" residual
    }
}

// ---------------- kernel 1: vp = v @ lin_w.T  -> bf16 [N][128] -----------------
__global__ __launch_bounds__(256) void vp_gemm(const float* __restrict__ v,
                                               const float* __restrict__ lin_w,
                                               unsigned short* __restrict__ vp, int nnodes) {
    const int tid = threadIdx.x;
    const int lane = tid & 63;
    const int wv = tid >> 6;          // wave 0..3 -> col strip of 32
    const int l15 = lane & 15;
    const int l4 = lane >> 4;
    const int r0 = blockIdx.x * 64;
    const int c0 = wv * 32;

    f32x4 acc[4][2] = {};
#pragma unroll
    for (int kf = 0; kf < 4; ++kf) {
        short8 a[4];
#pragma unroll
        for (int mf = 0; mf < 4; ++mf) {
            int row = r0 + mf * 16 + l15;
            f32x4 x0 = {}, x1 = {};
            if (row < nnodes) {
                const float* p = v + (size_t)row * 128 + kf * 32 + l4 * 8;
                x0 = *reinterpret_cast<const f32x4*>(p);
                x1 = *reinterpret_cast<const f32x4*>(p + 4);
            }
            a[mf] = pack4(cvt_pk_bf16(x0[0], x0[1]), cvt_pk_bf16(x0[2], x0[3]),
                          cvt_pk_bf16(x1[0], x1[1]), cvt_pk_bf16(x1[2], x1[3]));
        }
        short8 b[2];
#pragma unroll
        for (int nf = 0; nf < 2; ++nf) {
            const float* p = lin_w + (size_t)(c0 + nf * 16 + l15) * 128 + kf * 32 + l4 * 8;
            f32x4 x0 = *reinterpret_cast<const f32x4*>(p);
            f32x4 x1 = *reinterpret_cast<const f32x4*>(p + 4);
            b[nf] = pack4(cvt_pk_bf16(x0[0], x0[1]), cvt_pk_bf16(x0[2], x0[3]),
                          cvt_pk_bf16(x1[0], x1[1]), cvt_pk_bf16(x1[2], x1[3]));
        }
#pragma unroll
        for (int mf = 0; mf < 4; ++mf)
#pragma unroll
            for (int nf = 0; nf < 2; ++nf)
                acc[mf][nf] = __builtin_amdgcn_mfma_f32_16x16x32_bf16(a[mf], b[nf], acc[mf][nf], 0, 0, 0);
    }
#pragma unroll
    for (int mf = 0; mf < 4; ++mf)
#pragma unroll
        for (int nf = 0; nf < 2; ++nf)
#pragma unroll
            for (int q = 0; q < 4; ++q) {
                int row = r0 + mf * 16 + l4 * 4 + q;
                if (row < nnodes)
                    vp[(size_t)row * 128 + c0 + nf * 16 + l15] = f2bf(acc[mf][nf][q]);
            }
}

// ---------------- kernel 2: fused edge chain, LDS-staged weights --------------
// 4 waves x 64 edges. Weights double-buffered in LDS (32KB slots), prefetched
// one stage ahead via global_load_lds; B-reads are conflict-free ds_read_b128.
// launch_bounds(256,1): 512-reg budget -> zero spill, deep load pipelining.
__global__ __launch_bounds__(256, 1) void fused_edge(
    const float* __restrict__ dist, const float* __restrict__ dist_emb,
    const int* __restrict__ edge_index,
    const float* __restrict__ b1, const float* __restrict__ b2,
    const float* __restrict__ b3, const float* __restrict__ bo,
    const unsigned short* __restrict__ vp,
    const unsigned short* __restrict__ w1s, const unsigned short* __restrict__ w2s,
    const unsigned short* __restrict__ w3s, const unsigned short* __restrict__ wos,
    float* __restrict__ out) {
    __shared__ __align__(16) unsigned char lds_h[4][16384];    // per-wave h, swizzled
    __shared__ __align__(16) unsigned short wbuf[2][16384];    // weight dbuf, swizzled

    const int tid = threadIdx.x;
    const int lane = tid & 63;
    const int wv = tid >> 6;
    const int l15 = lane & 15;
    const int l4 = lane >> 4;
    const long e0 = (long)blockIdx.x * 256 + wv * 64;
    unsigned char* hb = lds_h[wv];

#define STAGE_W(src, buf)                                                  \
    _Pragma("unroll")                                                      \
    for (int it = 0; it < 8; ++it) {                                       \
        int chunk = it * 4 + wv;                                           \
        GLOAD_LDS16((src) + chunk * 512 + lane * 8, &wbuf[buf][chunk * 512]); \
    }

    // prologue: stage w1 -> buf0, w2 -> buf1; hoist indices + biases
    STAGE_W(w1s, 0)
    STAGE_W(w2s, 1)

    int jm[4];
#pragma unroll
    for (int mf = 0; mf < 4; ++mf)
        jm[mf] = edge_index[e0 + mf * 16 + l15] * 128;
    float bb1[8], bb2[8], bb3[8], bbo[8];
#pragma unroll
    for (int nf = 0; nf < 8; ++nf) {
        bb1[nf] = b1[nf * 16 + l15];
        bb2[nf] = b2[nf * 16 + l15];
        bb3[nf] = b3[nf * 16 + l15];
        bbo[nf] = bo[nf * 16 + l15];
    }

    f32x4 acc[4][8];

#define EPILOGUE_TO_LDS()                                                           \
    _Pragma("unroll")                                                               \
    for (int mf = 0; mf < 4; ++mf)                                                  \
        _Pragma("unroll")                                                           \
        for (int nf = 0; nf < 8; ++nf) {                                            \
            f32x4 vv = acc[mf][nf];                                                 \
            _Pragma("unroll")                                                       \
            for (int q = 0; q < 4; ++q) vv[q] = fmaxf(vv[q], SLOPE * vv[q]);        \
            unsigned p01 = cvt_pk_bf16(vv[0], vv[1]);                               \
            unsigned p23 = cvt_pk_bf16(vv[2], vv[3]);                               \
            int col2 = (nf * 16 + l15) * 2;                                         \
            int rb = mf * 16 + l4 * 4;                                              \
            *(unsigned short*)(hb + (rb + 0) * 256 + (col2 ^ ((l4 * 4 + 0) << 4))) = (unsigned short)p01;         \
            *(unsigned short*)(hb + (rb + 1) * 256 + (col2 ^ ((l4 * 4 + 1) << 4))) = (unsigned short)(p01 >> 16); \
            *(unsigned short*)(hb + (rb + 2) * 256 + (col2 ^ ((l4 * 4 + 2) << 4))) = (unsigned short)p23;         \
            *(unsigned short*)(hb + (rb + 3) * 256 + (col2 ^ ((l4 * 4 + 3) << 4))) = (unsigned short)(p23 >> 16); \
        }

#define HB_READ(mf, kf) \
    (*reinterpret_cast<const short8*>(hb + ((mf) * 16 + l15) * 256 + (((kf) * 64 + l4 * 16) ^ (l15 << 4))))
#define WB_READ(buf, nf, kf) \
    (*reinterpret_cast<const short8*>(&wbuf[buf][((nf) * 16 + l15) * 128 + (((kf) * 32 + l4 * 8) ^ (l15 << 3))]))

    __syncthreads();   // w1 (buf0) + w2 (buf1) staged

    // ================= stage 1: h1 = leaky(emb @ w1.T + b1) ==================
#pragma unroll
    for (int nf = 0; nf < 8; ++nf) {
        float b = bb1[nf];
#pragma unroll
        for (int mf = 0; mf < 4; ++mf) acc[mf][nf] = (f32x4){b, b, b, b};
    }
#pragma unroll
    for (int kf = 0; kf < 2; ++kf) {
        short8 a[4];
#pragma unroll
        for (int mf = 0; mf < 4; ++mf) {
            const float* src = dist_emb + (e0 + mf * 16 + l15) * 50 + kf * 32 + l4 * 8;
            unsigned pk[4];
#pragma unroll
            for (int p = 0; p < 4; ++p) {
                int k2 = kf * 32 + l4 * 8 + 2 * p;
                f32x2 x = (k2 < 50) ? *reinterpret_cast<const f32x2*>(src + 2 * p)
                                    : (f32x2){0.f, 0.f};
                pk[p] = cvt_pk_bf16(x[0], x[1]);
            }
            a[mf] = pack4(pk[0], pk[1], pk[2], pk[3]);
        }
#pragma unroll
        for (int nf = 0; nf < 8; ++nf) {
            short8 b = WB_READ(0, nf, kf);
#pragma unroll
            for (int mf = 0; mf < 4; ++mf)
                acc[mf][nf] = __builtin_amdgcn_mfma_f32_16x16x32_bf16(a[mf], b, acc[mf][nf], 0, 0, 0);
        }
    }
    EPILOGUE_TO_LDS()

    __syncthreads();   // all waves done reading buf0 (w1)
    STAGE_W(w3s, 0)    // prefetch w3 into buf0; hides under stage 2

    // ================= stage 2: h2 = leaky(h1 @ w2.T + b2) ====================
#pragma unroll
    for (int nf = 0; nf < 8; ++nf) {
        float b = bb2[nf];
#pragma unroll
        for (int mf = 0; mf < 4; ++mf) acc[mf][nf] = (f32x4){b, b, b, b};
    }
#pragma unroll
    for (int kf = 0; kf < 4; ++kf) {
        short8 a[4];
#pragma unroll
        for (int mf = 0; mf < 4; ++mf) a[mf] = HB_READ(mf, kf);
#pragma unroll
        for (int nf = 0; nf < 8; ++nf) {
            short8 b = WB_READ(1, nf, kf);
#pragma unroll
            for (int mf = 0; mf < 4; ++mf)
                acc[mf][nf] = __builtin_amdgcn_mfma_f32_16x16x32_bf16(a[mf], b, acc[mf][nf], 0, 0, 0);
        }
    }
    EPILOGUE_TO_LDS()

    __syncthreads();   // waves done with buf1 (w2); w3 staging drained
    STAGE_W(wos, 1)    // prefetch wo into buf1; hides under stage 3

    // ====== stage 3: W = (h2 @ w3.T + b3) * C  -> LDS (bf16) ==================
    {
        // vp gather prefetch: issued NOW, consumed in stage 4 (latency hidden
        // under stage-3 ds_reads + MFMAs). 64 VGPRs, affordable at 512 budget.
        short8 vpr[4][4];
#pragma unroll
        for (int mf = 0; mf < 4; ++mf)
#pragma unroll
            for (int kf = 0; kf < 4; ++kf)
                vpr[mf][kf] = *reinterpret_cast<const short8*>(vp + jm[mf] + kf * 32 + l4 * 8);

        float dd[4][4];
#pragma unroll
        for (int mf = 0; mf < 4; ++mf)
#pragma unroll
            for (int q = 0; q < 4; ++q)
                dd[mf][q] = dist[e0 + mf * 16 + l4 * 4 + q];

#pragma unroll
        for (int nf = 0; nf < 8; ++nf) {
            float b = bb3[nf];
#pragma unroll
            for (int mf = 0; mf < 4; ++mf) acc[mf][nf] = (f32x4){b, b, b, b};
        }
#pragma unroll
        for (int kf = 0; kf < 4; ++kf) {
            short8 a[4];
#pragma unroll
            for (int mf = 0; mf < 4; ++mf) a[mf] = HB_READ(mf, kf);
#pragma unroll
            for (int nf = 0; nf < 8; ++nf) {
                short8 b = WB_READ(0, nf, kf);
#pragma unroll
                for (int mf = 0; mf < 4; ++mf)
                    acc[mf][nf] = __builtin_amdgcn_mfma_f32_16x16x32_bf16(a[mf], b, acc[mf][nf], 0, 0, 0);
            }
        }
        float Cw[4][4];
#pragma unroll
        for (int mf = 0; mf < 4; ++mf)
#pragma unroll
            for (int q = 0; q < 4; ++q)
                Cw[mf][q] = 0.5f * (__cosf(dd[mf][q] * PI_OVER_CUTOFF) + 1.0f);
#pragma unroll
        for (int mf = 0; mf < 4; ++mf)
#pragma unroll
            for (int nf = 0; nf < 8; ++nf) {
                f32x4 vv = acc[mf][nf];
#pragma unroll
                for (int q = 0; q < 4; ++q) vv[q] = vv[q] * Cw[mf][q];
                unsigned p01 = cvt_pk_bf16(vv[0], vv[1]);
                unsigned p23 = cvt_pk_bf16(vv[2], vv[3]);
                int col2 = (nf * 16 + l15) * 2;
                int rb = mf * 16 + l4 * 4;
                *(unsigned short*)(hb + (rb + 0) * 256 + (col2 ^ ((l4 * 4 + 0) << 4))) = (unsigned short)p01;
                *(unsigned short*)(hb + (rb + 1) * 256 + (col2 ^ ((l4 * 4 + 1) << 4))) = (unsigned short)(p01 >> 16);
                *(unsigned short*)(hb + (rb + 2) * 256 + (col2 ^ ((l4 * 4 + 2) << 4))) = (unsigned short)p23;
                *(unsigned short*)(hb + (rb + 3) * 256 + (col2 ^ ((l4 * 4 + 3) << 4))) = (unsigned short)(p23 >> 16);
            }

        __syncthreads();   // waves done with buf0 (w3); wo staging drained

        // ====== stage 4: out = (vp[j] .* W) @ (wo + I).T + bo =================
#pragma unroll
        for (int nf = 0; nf < 8; ++nf) {
            float b = bbo[nf];
#pragma unroll
            for (int mf = 0; mf < 4; ++mf) acc[mf][nf] = (f32x4){b, b, b, b};
        }
#pragma unroll
        for (int kf = 0; kf < 4; ++kf) {
            short8 a[4];
#pragma unroll
            for (int mf = 0; mf < 4; ++mf) a[mf] = mulbf8(HB_READ(mf, kf), vpr[mf][kf]);
#pragma unroll
            for (int nf = 0; nf < 8; ++nf) {
                short8 b = WB_READ(1, nf, kf);
#pragma unroll
                for (int mf = 0; mf < 4; ++mf)
                    acc[mf][nf] = __builtin_amdgcn_mfma_f32_16x16x32_bf16(a[mf], b, acc[mf][nf], 0, 0, 0);
            }
        }
        float* op = out + (size_t)e0 * 128;
#pragma unroll
        for (int mf = 0; mf < 4; ++mf)
#pragma unroll
            for (int nf = 0; nf < 8; ++nf)
#pragma unroll
                for (int q = 0; q < 4; ++q)
                    op[(size_t)(mf * 16 + l4 * 4 + q) * 128 + nf * 16 + l15] = acc[mf][nf][q];
    }
#undef EPILOGUE_TO_LDS
#undef HB_READ
#undef WB_READ
#undef STAGE_W
}

extern "C" void kernel_launch(void* const* d_in, const int* in_sizes, int n_in,
                              void* d_out, int out_size, void* d_ws, size_t ws_size,
                              hipStream_t stream) {
    const float* v        = (const float*)d_in[0];
    const float* dist     = (const float*)d_in[1];
    const float* dist_emb = (const float*)d_in[2];
    const int*   edge_idx = (const int*)d_in[3];
    const float* lin_w    = (const float*)d_in[4];
    const float* w1 = (const float*)d_in[5];
    const float* b1 = (const float*)d_in[6];
    const float* w2 = (const float*)d_in[7];
    const float* b2 = (const float*)d_in[8];
    const float* w3 = (const float*)d_in[9];
    const float* b3 = (const float*)d_in[10];
    const float* wo = (const float*)d_in[11];
    const float* bo = (const float*)d_in[12];
    float* out = (float*)d_out;

    const int nnodes = in_sizes[0] / 128;   // 50000
    const int E = in_sizes[1];              // 1600000 (multiple of 256)

    unsigned short* vp  = (unsigned short*)d_ws;            // [nnodes][128] bf16
    unsigned short* w1s = vp + (size_t)nnodes * 128;        // [128][128] swizzled (padded)
    unsigned short* w2s = w1s + 128 * 128;
    unsigned short* w3s = w2s + 128 * 128;
    unsigned short* wos = w3s + 128 * 128;

    prep_weights<<<64, 256, 0, stream>>>(w1, w2, w3, wo, w1s, w2s, w3s, wos);
    vp_gemm<<<(nnodes + 63) / 64, 256, 0, stream>>>(v, lin_w, vp, nnodes);
    fused_edge<<<E / 256, 256, 0, stream>>>(dist, dist_emb, edge_idx,
                                            b1, b2, b3, bo, vp,
                                            w1s, w2s, w3s, wos, out);
}